// Round 1
// baseline (184.557 us; speedup 1.0000x reference)
//
#include <hip/hip_runtime.h>

// RejectionSampler: greedy argmax over 2048 x 128000 f32 logits, then
// per-sequence accept logic (B=256, K=7, S=8).
//
// d_out layout (int32): [0,2048) accept_tokens | [2048,2304) starts | [2304,2560) num_accepted

#define BLK 256

__global__ __launch_bounds__(BLK) void rs_argmax_kernel(
    const float* __restrict__ logits, int* __restrict__ out_idx, int v4 /* vocab/4 */) {
    const int row = blockIdx.x;
    const float4* __restrict__ p =
        reinterpret_cast<const float4*>(logits + (size_t)row * (size_t)(v4 * 4));

    float best = -INFINITY;
    int bestIdx = 0x7fffffff;

    // Per-thread indices strictly increase, so strict '>' keeps the first occurrence.
    for (int i = threadIdx.x; i < v4; i += BLK) {
        float4 v = p[i];
        int base = i * 4;
        if (v.x > best) { best = v.x; bestIdx = base; }
        if (v.y > best) { best = v.y; bestIdx = base + 1; }
        if (v.z > best) { best = v.z; bestIdx = base + 2; }
        if (v.w > best) { best = v.w; bestIdx = base + 3; }
    }

    // Wave (64-lane) reduction with lowest-index tie-break.
    for (int off = 32; off > 0; off >>= 1) {
        float ov = __shfl_down(best, off, 64);
        int   oi = __shfl_down(bestIdx, off, 64);
        if (ov > best || (ov == best && oi < bestIdx)) { best = ov; bestIdx = oi; }
    }

    __shared__ float sval[BLK / 64];
    __shared__ int   sidx[BLK / 64];
    const int wave = threadIdx.x >> 6;
    const int lane = threadIdx.x & 63;
    if (lane == 0) { sval[wave] = best; sidx[wave] = bestIdx; }
    __syncthreads();
    if (threadIdx.x == 0) {
        best = sval[0]; bestIdx = sidx[0];
        #pragma unroll
        for (int w = 1; w < BLK / 64; ++w) {
            if (sval[w] > best || (sval[w] == best && sidx[w] < bestIdx)) {
                best = sval[w]; bestIdx = sidx[w];
            }
        }
        out_idx[row] = bestIdx;
    }
}

// One block of 256 threads: thread b handles sequence b.
__global__ __launch_bounds__(BLK) void rs_finalize_kernel(
    const int* __restrict__ sample,  // [B*S] argmax tokens
    const int* __restrict__ draft,   // [B*K]
    int* __restrict__ out) {
    const int B = 256, K = 7, S = 8;
    const int b = threadIdx.x;

    // Zero the accept_tokens region (harness poisons d_out; untouched slots must be 0).
    for (int i = threadIdx.x; i < B * S; i += BLK) out[i] = 0;

    // Prefix match. NOTE: faithful to reference — sample is indexed with K-stride here.
    int dtk[7];
    int j = 0;
    bool good = true;
    #pragma unroll
    for (int p = 0; p < K; ++p) {
        dtk[p] = draft[b * K + p];
        if (good && sample[b * K + p] == dtk[p]) ++j;
        else good = false;
    }
    const int num_acc = j + 1;
    const int bonus = sample[b * S + j];   // S-stride for the bonus token

    // Exclusive scan of num_acc across the 256 sequences (Hillis-Steele, inclusive then subtract).
    __shared__ int scan[BLK];
    scan[b] = num_acc;
    __syncthreads();
    for (int off = 1; off < BLK; off <<= 1) {
        int v = (b >= off) ? scan[b - off] : 0;
        __syncthreads();
        scan[b] += v;
        __syncthreads();
    }
    const int start = scan[b] - num_acc;

    // Scatter accepted tokens (ranges are disjoint; zeroing completed before scan barriers).
    for (int p = 0; p < num_acc; ++p) {
        out[start + p] = (p < j) ? dtk[p] : bonus;
    }
    out[B * S + b] = start;
    out[B * S + B + b] = num_acc;
}

extern "C" void kernel_launch(void* const* d_in, const int* in_sizes, int n_in,
                              void* d_out, int out_size, void* d_ws, size_t ws_size,
                              hipStream_t stream) {
    const float* logits = (const float*)d_in[0];
    // d_in[1] = temperatures: all zero in this problem -> greedy branch only.
    const int* draft = (const int*)d_in[2];

    const int rows  = in_sizes[1];              // B*S = 2048
    const int vocab = (int)((long long)in_sizes[0] / rows);  // 128000
    int* sample = (int*)d_ws;                   // 2048 ints scratch

    rs_argmax_kernel<<<rows, BLK, 0, stream>>>(logits, sample, vocab / 4);
    rs_finalize_kernel<<<1, BLK, 0, stream>>>(sample, draft, (int*)d_out);
}

// Round 3
// 160.893 us; speedup vs baseline: 1.1471x; 1.1471x over previous
//
#include <hip/hip_runtime.h>

// RejectionSampler: greedy argmax over 2048 x 128000 f32 logits, then
// per-sequence accept logic (B=256, K=7, S=8).
//
// d_out layout (int32): [0,2048) accept_tokens | [2048,2304) starts | [2304,2560) num_accepted
//
// R3: same as R2 (unroll-5, 5 independent accumulator streams, NT loads) but
// with a clang ext_vector float4 so __builtin_nontemporal_load accepts it.

#define BLK 256

typedef float f32x4 __attribute__((ext_vector_type(4)));

__global__ __launch_bounds__(BLK) void rs_argmax_kernel(
    const float* __restrict__ logits, int* __restrict__ out_idx, int v4 /* vocab/4 */) {
    const int row = blockIdx.x;
    const f32x4* __restrict__ p =
        reinterpret_cast<const f32x4*>(logits + (size_t)row * (size_t)(v4 * 4));

    // 5 independent accumulator streams. Within a stream, per-thread indices
    // strictly increase, so '>' keeps the first occurrence.
    float bv0 = -INFINITY, bv1 = -INFINITY, bv2 = -INFINITY, bv3 = -INFINITY, bv4 = -INFINITY;
    int   bi0 = 0x7fffffff, bi1 = 0x7fffffff, bi2 = 0x7fffffff, bi3 = 0x7fffffff, bi4 = 0x7fffffff;

    int i = threadIdx.x;
    const int stride = BLK;
    for (; i + 4 * stride < v4; i += 5 * stride) {
        f32x4 v0 = __builtin_nontemporal_load(&p[i]);
        f32x4 v1 = __builtin_nontemporal_load(&p[i + stride]);
        f32x4 v2 = __builtin_nontemporal_load(&p[i + 2 * stride]);
        f32x4 v3 = __builtin_nontemporal_load(&p[i + 3 * stride]);
        f32x4 v4q = __builtin_nontemporal_load(&p[i + 4 * stride]);
        int b0 = i * 4, b1 = (i + stride) * 4, b2 = (i + 2 * stride) * 4,
            b3 = (i + 3 * stride) * 4, b4 = (i + 4 * stride) * 4;
        if (v0.x > bv0) { bv0 = v0.x; bi0 = b0; }
        if (v0.y > bv0) { bv0 = v0.y; bi0 = b0 + 1; }
        if (v0.z > bv0) { bv0 = v0.z; bi0 = b0 + 2; }
        if (v0.w > bv0) { bv0 = v0.w; bi0 = b0 + 3; }
        if (v1.x > bv1) { bv1 = v1.x; bi1 = b1; }
        if (v1.y > bv1) { bv1 = v1.y; bi1 = b1 + 1; }
        if (v1.z > bv1) { bv1 = v1.z; bi1 = b1 + 2; }
        if (v1.w > bv1) { bv1 = v1.w; bi1 = b1 + 3; }
        if (v2.x > bv2) { bv2 = v2.x; bi2 = b2; }
        if (v2.y > bv2) { bv2 = v2.y; bi2 = b2 + 1; }
        if (v2.z > bv2) { bv2 = v2.z; bi2 = b2 + 2; }
        if (v2.w > bv2) { bv2 = v2.w; bi2 = b2 + 3; }
        if (v3.x > bv3) { bv3 = v3.x; bi3 = b3; }
        if (v3.y > bv3) { bv3 = v3.y; bi3 = b3 + 1; }
        if (v3.z > bv3) { bv3 = v3.z; bi3 = b3 + 2; }
        if (v3.w > bv3) { bv3 = v3.w; bi3 = b3 + 3; }
        if (v4q.x > bv4) { bv4 = v4q.x; bi4 = b4; }
        if (v4q.y > bv4) { bv4 = v4q.y; bi4 = b4 + 1; }
        if (v4q.z > bv4) { bv4 = v4q.z; bi4 = b4 + 2; }
        if (v4q.w > bv4) { bv4 = v4q.w; bi4 = b4 + 3; }
    }
    // Tail (none for v4=32000, BLK=256, but keep generic).
    for (; i < v4; i += stride) {
        f32x4 v = __builtin_nontemporal_load(&p[i]);
        int base = i * 4;
        if (v.x > bv0) { bv0 = v.x; bi0 = base; }
        if (v.y > bv0) { bv0 = v.y; bi0 = base + 1; }
        if (v.z > bv0) { bv0 = v.z; bi0 = base + 2; }
        if (v.w > bv0) { bv0 = v.w; bi0 = base + 3; }
    }

    // Merge the 5 streams (lowest-index tie-break).
    float best = bv0; int bestIdx = bi0;
    if (bv1 > best || (bv1 == best && bi1 < bestIdx)) { best = bv1; bestIdx = bi1; }
    if (bv2 > best || (bv2 == best && bi2 < bestIdx)) { best = bv2; bestIdx = bi2; }
    if (bv3 > best || (bv3 == best && bi3 < bestIdx)) { best = bv3; bestIdx = bi3; }
    if (bv4 > best || (bv4 == best && bi4 < bestIdx)) { best = bv4; bestIdx = bi4; }

    // Wave (64-lane) reduction with lowest-index tie-break.
    for (int off = 32; off > 0; off >>= 1) {
        float ov = __shfl_down(best, off, 64);
        int   oi = __shfl_down(bestIdx, off, 64);
        if (ov > best || (ov == best && oi < bestIdx)) { best = ov; bestIdx = oi; }
    }

    __shared__ float sval[BLK / 64];
    __shared__ int   sidx[BLK / 64];
    const int wave = threadIdx.x >> 6;
    const int lane = threadIdx.x & 63;
    if (lane == 0) { sval[wave] = best; sidx[wave] = bestIdx; }
    __syncthreads();
    if (threadIdx.x == 0) {
        best = sval[0]; bestIdx = sidx[0];
        #pragma unroll
        for (int w = 1; w < BLK / 64; ++w) {
            if (sval[w] > best || (sval[w] == best && sidx[w] < bestIdx)) {
                best = sval[w]; bestIdx = sidx[w];
            }
        }
        out_idx[row] = bestIdx;
    }
}

// One block of 256 threads: thread b handles sequence b.
__global__ __launch_bounds__(BLK) void rs_finalize_kernel(
    const int* __restrict__ sample,  // [B*S] argmax tokens
    const int* __restrict__ draft,   // [B*K]
    int* __restrict__ out) {
    const int B = 256, K = 7, S = 8;
    const int b = threadIdx.x;

    // Zero the accept_tokens region (harness poisons d_out; untouched slots must be 0).
    for (int i = threadIdx.x; i < B * S; i += BLK) out[i] = 0;

    // Prefix match. NOTE: faithful to reference — sample is indexed with K-stride here.
    int dtk[7];
    int j = 0;
    bool good = true;
    #pragma unroll
    for (int p = 0; p < K; ++p) {
        dtk[p] = draft[b * K + p];
        if (good && sample[b * K + p] == dtk[p]) ++j;
        else good = false;
    }
    const int num_acc = j + 1;
    const int bonus = sample[b * S + j];   // S-stride for the bonus token

    // Exclusive scan of num_acc across the 256 sequences (Hillis-Steele).
    __shared__ int scan[BLK];
    scan[b] = num_acc;
    __syncthreads();
    for (int off = 1; off < BLK; off <<= 1) {
        int v = (b >= off) ? scan[b - off] : 0;
        __syncthreads();
        scan[b] += v;
        __syncthreads();
    }
    const int start = scan[b] - num_acc;

    // Scatter accepted tokens (ranges are disjoint; zeroing completed before scan barriers).
    for (int p = 0; p < num_acc; ++p) {
        out[start + p] = (p < j) ? dtk[p] : bonus;
    }
    out[B * S + b] = start;
    out[B * S + B + b] = num_acc;
}

extern "C" void kernel_launch(void* const* d_in, const int* in_sizes, int n_in,
                              void* d_out, int out_size, void* d_ws, size_t ws_size,
                              hipStream_t stream) {
    const float* logits = (const float*)d_in[0];
    // d_in[1] = temperatures: all zero in this problem -> greedy branch only.
    const int* draft = (const int*)d_in[2];

    const int rows  = in_sizes[1];              // B*S = 2048
    const int vocab = (int)((long long)in_sizes[0] / rows);  // 128000
    int* sample = (int*)d_ws;                   // 2048 ints scratch

    rs_argmax_kernel<<<rows, BLK, 0, stream>>>(logits, sample, vocab / 4);
    rs_finalize_kernel<<<1, BLK, 0, stream>>>(sample, draft, (int*)d_out);
}